// Round 4
// baseline (91.996 us; speedup 1.0000x reference)
//
#include <hip/hip_runtime.h>

#define THREADS 256
#define NBLK 1024  // 65536 rows / 64 per block

typedef _Float16 half8 __attribute__((ext_vector_type(8)));
typedef float floatx4 __attribute__((ext_vector_type(4)));

// --- Kernel 1: W [512(k)][512(n)] fp32 -> Wt [512(n)][512(k)] f16 ---
__global__ void wcvt_kernel(const float* __restrict__ W, unsigned short* __restrict__ Wt) {
  __shared__ float tile[32][33];
  const int tx = threadIdx.x, ty = threadIdx.y;
  const int nb = blockIdx.x * 32, kb = blockIdx.y * 32;
#pragma unroll
  for (int i = 0; i < 4; ++i)
    tile[ty + 8 * i][tx] = W[(size_t)(kb + ty + 8 * i) * 512 + nb + tx];
  __syncthreads();
#pragma unroll
  for (int i = 0; i < 4; ++i) {
    union { _Float16 h; unsigned short u; } v;
    v.h = (_Float16)tile[tx][ty + 8 * i];
    Wt[(size_t)(nb + ty + 8 * i) * 512 + kb + tx] = v.u;
  }
}

// --- Kernel 2: fused GEMM + surrogate-sigmoid + rowwise LayerNorm ---
// Block tile: 64 rows x 512 cols, 4 waves (1x4), wave tile 64x128.
// LDS = 80 KB exactly -> 2 independent blocks/CU (cross-block latency hiding).
// All-DMA staging, double-buffered; refill of a buffer is issued ONLY after the
// post-MFMA barrier proves every wave consumed it (fixes r3's refill race).
// LDS (bytes):
//   [0, 16384)      : A fp32, 2 bufs x 8192  (64 rows x 8 slots x 16B, XOR-swizzled)
//   [16384, 81920)  : B f16,  2 bufs x 32768 (512 rows x 4 slots x 16B, XOR-swizzled)
//   reduction scratch aliases A region after the K-loop.
#define ABUF 8192
#define BBASE 16384
#define BBUF 32768

__global__ __launch_bounds__(THREADS, 2) void lif_fused_kernel(
    const float* __restrict__ A, const unsigned short* __restrict__ Wt,
    const float* __restrict__ bias, const float* __restrict__ lnw,
    const float* __restrict__ lnb, float* __restrict__ out) {
  __shared__ uint4 smem4[5120];  // 81920 bytes
  unsigned char* smem = (unsigned char*)smem4;

  const int tid  = threadIdx.x;
  const int lane = tid & 63;
  const int wave = tid >> 6;   // 0..3
  const int wcol = wave;       // wave tile: all 64 rows x cols [wcol*128, +128)
  const int l15  = lane & 15;
  const int g    = lane >> 4;  // 0..3
  const int rowBase = blockIdx.x * 64;

  // Staging source addresses (inverse-swizzled global, linear LDS dest).
  const int bslot = (tid & 3) ^ ((tid >> 3) & 3);
  const int aslot = (tid & 7) ^ ((tid >> 3) & 7);
  const unsigned short* bsrc = Wt + (size_t)(tid >> 2) * 512 + bslot * 8;
  const float* asrc = A + (size_t)(rowBase + (tid >> 3)) * 512 + aslot * 4;

  auto stage = [&](int buf, int kk) {
#pragma unroll
    for (int i = 0; i < 8; ++i) {  // B: 512 rows x 32k f16 = 32 KB
      int off = BBASE + buf * BBUF + i * 4096 + wave * 1024;
      off = __builtin_amdgcn_readfirstlane(off);
      __builtin_amdgcn_global_load_lds(
          (const __attribute__((address_space(1))) void*)(bsrc + (size_t)i * 32768 + kk * 32),
          (__attribute__((address_space(3))) void*)(smem + off), 16, 0, 0);
    }
#pragma unroll
    for (int j = 0; j < 2; ++j) {  // A: 64 rows x 32k fp32 = 8 KB
      int off = buf * ABUF + j * 4096 + wave * 1024;
      off = __builtin_amdgcn_readfirstlane(off);
      __builtin_amdgcn_global_load_lds(
          (const __attribute__((address_space(1))) void*)(asrc + (size_t)j * 16384 + kk * 32),
          (__attribute__((address_space(3))) void*)(smem + off), 16, 0, 0);
    }
  };

  // Fragment read offsets.
  const int aswz = l15 & 7;
  const int aOff0 = ((g << 1) ^ aswz) << 4;  // logical slot 2g
  const int aOff1 = aOff0 ^ 16;              // logical slot 2g+1
  const int aRowOff = l15 * 128;             // + m*2048 + buf*ABUF
  const int bRowOff = (wcol * 128 + l15) * 64;  // + n*1024 + buf*BBUF
  const int bsw = (g ^ ((l15 >> 1) & 3)) << 4;

  floatx4 acc[4][8];
#pragma unroll
  for (int m = 0; m < 4; ++m)
#pragma unroll
    for (int n = 0; n < 8; ++n)
      acc[m][n] = (floatx4){0.f, 0.f, 0.f, 0.f};

  stage(0, 0);
  stage(1, 1);

#pragma unroll
  for (int k = 0; k < 16; ++k) {
    if (k < 15) {
      asm volatile("s_waitcnt vmcnt(10)" ::: "memory");  // stage k landed; k+1 in flight
    } else {
      asm volatile("s_waitcnt vmcnt(0)" ::: "memory");
    }
    __builtin_amdgcn_s_barrier();
    __builtin_amdgcn_sched_barrier(0);

    const int buf = k & 1;
    const unsigned char* abase = smem + buf * ABUF + aRowOff;
    half8 a[4];
#pragma unroll
    for (int m = 0; m < 4; ++m) {
      float4 lo = *(const float4*)(abase + m * 2048 + aOff0);
      float4 hi = *(const float4*)(abase + m * 2048 + aOff1);
      half8 t;
      t[0] = (_Float16)lo.x; t[1] = (_Float16)lo.y;
      t[2] = (_Float16)lo.z; t[3] = (_Float16)lo.w;
      t[4] = (_Float16)hi.x; t[5] = (_Float16)hi.y;
      t[6] = (_Float16)hi.z; t[7] = (_Float16)hi.w;
      a[m] = t;
    }
    const unsigned char* bbase = smem + BBASE + buf * BBUF + bRowOff + bsw;
    __builtin_amdgcn_s_setprio(1);
#pragma unroll
    for (int n = 0; n < 8; ++n) {
      half8 bf = *(const half8*)(bbase + n * 1024);
      acc[0][n] = __builtin_amdgcn_mfma_f32_16x16x32_f16(a[0], bf, acc[0][n], 0, 0, 0);
      acc[1][n] = __builtin_amdgcn_mfma_f32_16x16x32_f16(a[1], bf, acc[1][n], 0, 0, 0);
      acc[2][n] = __builtin_amdgcn_mfma_f32_16x16x32_f16(a[2], bf, acc[2][n], 0, 0, 0);
      acc[3][n] = __builtin_amdgcn_mfma_f32_16x16x32_f16(a[3], bf, acc[3][n], 0, 0, 0);
    }
    __builtin_amdgcn_s_setprio(0);
    __builtin_amdgcn_sched_barrier(0);
    // All waves' fragment reads for `buf` are complete (consumed into registers
    // by the MFMAs above) once every wave reaches this barrier. Only AFTER it
    // is it safe to issue the DMA refill of `buf` (r3's bug: issuing before).
    __builtin_amdgcn_s_barrier();
    __builtin_amdgcn_sched_barrier(0);
    if (k < 14) stage(buf, k + 2);
  }
  __syncthreads();

  // --- Epilogue: bias + surrogate spike + fused LayerNorm ---
  float bcol[8], lsc[8], lbc[8];
#pragma unroll
  for (int n = 0; n < 8; ++n) {
    const int col = wcol * 128 + n * 16 + l15;
    bcol[n] = bias[col];
    lsc[n]  = lnw[col];
    lbc[n]  = lnb[col];
  }
#pragma unroll
  for (int m = 0; m < 4; ++m)
#pragma unroll
    for (int n = 0; n < 8; ++n)
#pragma unroll
      for (int r = 0; r < 4; ++r) {
        // alpha=exp(-50): v == current in fp32; spike = fast_sigmoid(v - 0.5, 4)
        float x  = acc[m][n][r] + bcol[n] - 0.5f;
        float bx = 4.0f * x;
        acc[m][n][r] = 0.5f * bx / (1.0f + fabsf(bx)) + 0.5f;
      }

  float rs[4][4], rq[4][4];
#pragma unroll
  for (int m = 0; m < 4; ++m)
#pragma unroll
    for (int r = 0; r < 4; ++r) {
      float s = 0.f, q = 0.f;
#pragma unroll
      for (int n = 0; n < 8; ++n) {
        float v = acc[m][n][r];
        s += v;
        q += v * v;
      }
      rs[m][r] = s;
      rq[m][r] = q;
    }
#pragma unroll
  for (int d = 1; d < 16; d <<= 1) {
#pragma unroll
    for (int m = 0; m < 4; ++m)
#pragma unroll
      for (int r = 0; r < 4; ++r) {
        rs[m][r] += __shfl_xor(rs[m][r], d, 16);
        rq[m][r] += __shfl_xor(rq[m][r], d, 16);
      }
  }

  float* redS = (float*)smem4;   // [64][4]
  float* redQ = redS + 256;      // [64][4]
  float* mv   = redQ + 256;      // [64][2]
  if (l15 == 0) {
#pragma unroll
    for (int m = 0; m < 4; ++m)
#pragma unroll
      for (int r = 0; r < 4; ++r) {
        const int row = m * 16 + g * 4 + r;
        redS[row * 4 + wcol] = rs[m][r];
        redQ[row * 4 + wcol] = rq[m][r];
      }
  }
  __syncthreads();
  if (tid < 64) {
    const float S = redS[tid * 4] + redS[tid * 4 + 1] + redS[tid * 4 + 2] + redS[tid * 4 + 3];
    const float Q = redQ[tid * 4] + redQ[tid * 4 + 1] + redQ[tid * 4 + 2] + redQ[tid * 4 + 3];
    const float mean = S * (1.0f / 512.0f);
    const float var  = Q * (1.0f / 512.0f) - mean * mean;
    mv[tid * 2]     = mean;
    mv[tid * 2 + 1] = rsqrtf(var + 1e-6f);
  }
  __syncthreads();

#pragma unroll
  for (int m = 0; m < 4; ++m)
#pragma unroll
    for (int r = 0; r < 4; ++r) {
      const int row  = m * 16 + g * 4 + r;
      const float mean = mv[row * 2];
      const float rstd = mv[row * 2 + 1];
      const size_t base = (size_t)(rowBase + row) * 512;
#pragma unroll
      for (int n = 0; n < 8; ++n) {
        const int col = wcol * 128 + n * 16 + l15;
        out[base + col] = (acc[m][n][r] - mean) * rstd * lsc[n] + lbc[n];
      }
    }
}

extern "C" void kernel_launch(void* const* d_in, const int* in_sizes, int n_in,
                              void* d_out, int out_size, void* d_ws, size_t ws_size,
                              hipStream_t stream) {
  const float* spikes = (const float*)d_in[0];
  const float* W      = (const float*)d_in[1];
  const float* b      = (const float*)d_in[2];
  const float* lnw    = (const float*)d_in[3];
  const float* lnb    = (const float*)d_in[4];
  float* out = (float*)d_out;
  unsigned short* Wt = (unsigned short*)d_ws;  // 512*512*2 = 512 KB scratch

  wcvt_kernel<<<dim3(16, 16), dim3(32, 8), 0, stream>>>(W, Wt);
  lif_fused_kernel<<<NBLK, THREADS, 0, stream>>>(spikes, Wt, b, lnw, lnb, out);
}